// Round 1
// baseline (88.892 us; speedup 1.0000x reference)
//
#include <hip/hip_runtime.h>
#include <hip/hip_bf16.h>

typedef __bf16 bf16x8 __attribute__((ext_vector_type(8)));
typedef float  f32x4  __attribute__((ext_vector_type(4)));
typedef float  f32x8  __attribute__((ext_vector_type(8)));

#define MFMA16(a, b, c) __builtin_amdgcn_mfma_f32_16x16x32_bf16((a), (b), (c), 0, 0, 0)

constexpr int J       = 24;
constexpr int C       = 64;
constexpr int ROW     = J * C;     // 1536 elems per batch (node/edge/out)
constexpr int WPITCH  = 72;        // WT row pitch in bf16 (64 + 8 pad) -> 144B rows, conflict-free b128
constexpr int KP      = 40;        // PT / adjT row pitch in bf16 -> 80B rows, 16B aligned
constexpr int BATCHES = 16384;
constexpr int BLOCKS  = 1024;
constexpr int BPW     = BATCHES / (BLOCKS * 4);  // 4 batches per wave

__global__ __launch_bounds__(256, 2) void n2e_kernel(
    const float* __restrict__ node, const float* __restrict__ edge,
    const float* __restrict__ adj,
    const float* __restrict__ Wp, const float* __restrict__ bp,
    const float* __restrict__ Wr, const float* __restrict__ br,
    const float* __restrict__ Wc, const float* __restrict__ bc,
    float* __restrict__ out)
{
    // Weights transposed: sW*[d*WPITCH + c] = W[c][d]  (B-operand friendly: lane reads 8 contiguous c)
    __shared__ alignas(16) __bf16 sWc[64 * WPITCH];
    __shared__ alignas(16) __bf16 sWr[64 * WPITCH];
    __shared__ alignas(16) __bf16 sWp[64 * WPITCH];
    __shared__ alignas(16) float  sBsum[64];   // b_child + b_rec
    __shared__ alignas(16) float  sBpar[64];   // b_parent
    __shared__ alignas(16) __bf16 sPT[4][64 * KP];    // per-wave: P^T[d][k] (+b_parent), k=24..31 zeroed
    __shared__ alignas(16) __bf16 sAdjT[4][32 * KP];  // per-wave: adjT[j][k] = adj[k][j], k=24..31 zeroed

    const int tid  = threadIdx.x;
    const int lane = tid & 63;
    const int wave = tid >> 6;
    const int r    = lane & 15;   // A/B frag row|col ; C frag col
    const int g    = lane >> 4;   // k-group

    // ---- stage weights (once per block) ----
    for (int idx = tid; idx < 4096; idx += 256) {
        int c = idx >> 6, d = idx & 63;
        sWc[d * WPITCH + c] = (__bf16)Wc[idx];
        sWr[d * WPITCH + c] = (__bf16)Wr[idx];
        sWp[d * WPITCH + c] = (__bf16)Wp[idx];
    }
    if (tid < 64) { sBsum[tid] = bc[tid] + br[tid]; sBpar[tid] = bp[tid]; }
    __syncthreads();

    __bf16* myPT = &sPT[wave][0];
    __bf16* myAT = &sAdjT[wave][0];

    for (int it = 0; it < BPW; ++it) {
        const int b = blockIdx.x * (4 * BPW) + wave * BPW + it;
        const float* nf = node + (size_t)b * ROW;
        const float* ef = edge + (size_t)b * ROW;
        const float* af = adj  + (size_t)b * (J * J);

        // ---- node/edge A-fragments (row = mt*16 + r, 8 contiguous k) ----
        bf16x8 aN[2][2], aE[2][2];
        #pragma unroll
        for (int mt = 0; mt < 2; ++mt) {
            const int row = mt * 16 + r;
            #pragma unroll
            for (int ks = 0; ks < 2; ++ks) {
                if (row < J) {
                    f32x8 v = *(const f32x8*)(nf + row * C + ks * 32 + g * 8);
                    f32x8 w = *(const f32x8*)(ef + row * C + ks * 32 + g * 8);
                    bf16x8 an, ae;
                    #pragma unroll
                    for (int e = 0; e < 8; ++e) { an[e] = (__bf16)v[e]; ae[e] = (__bf16)w[e]; }
                    aN[mt][ks] = an; aE[mt][ks] = ae;
                } else {
                    bf16x8 z{};
                    aN[mt][ks] = z; aE[mt][ks] = z;
                }
            }
        }

        // ---- zero adjT pad cols k=24..31 (rows 0..31); disjoint from scatter below ----
        {
            unsigned int* az = (unsigned int*)myAT;   // dword pitch = KP/2 = 20
            #pragma unroll
            for (int z = 0; z < 2; ++z) {
                int i   = z * 64 + lane;              // 0..127
                int row = i >> 2;
                int dc  = 12 + (i & 3);               // dwords 12..15 = k 24..31
                az[row * (KP / 2) + dc] = 0u;
            }
        }
        // ---- scatter adj transposed: adjT[j][k] = adj[k][j] ----
        #pragma unroll
        for (int z = 0; z < 9; ++z) {
            int i = z * 64 + lane;                    // 576 = 9*64 exactly
            float v = af[i];
            int k = i / 24;
            int j = i - k * 24;
            myAT[j * KP + k] = (__bf16)v;
        }

        // ---- children + recurrent: acc_cr[j-tile][d-tile] ----
        f32x4 accCR[2][4];
        #pragma unroll
        for (int mt = 0; mt < 2; ++mt)
            #pragma unroll
            for (int nt = 0; nt < 4; ++nt) accCR[mt][nt] = f32x4{0.f, 0.f, 0.f, 0.f};
        #pragma unroll
        for (int ks = 0; ks < 2; ++ks) {
            #pragma unroll
            for (int nt = 0; nt < 4; ++nt) {
                bf16x8 bC = *(const bf16x8*)(sWc + (nt * 16 + r) * WPITCH + ks * 32 + g * 8);
                bf16x8 bR = *(const bf16x8*)(sWr + (nt * 16 + r) * WPITCH + ks * 32 + g * 8);
                #pragma unroll
                for (int mt = 0; mt < 2; ++mt) {
                    accCR[mt][nt] = MFMA16(aN[mt][ks], bC, accCR[mt][nt]);
                    accCR[mt][nt] = MFMA16(aE[mt][ks], bR, accCR[mt][nt]);
                }
            }
        }

        // ---- P^T = Wp^T @ node^T : accP[d-tile][j-tile] ----
        f32x4 accP[4][2];
        #pragma unroll
        for (int mt = 0; mt < 4; ++mt)
            #pragma unroll
            for (int nt = 0; nt < 2; ++nt) accP[mt][nt] = f32x4{0.f, 0.f, 0.f, 0.f};
        #pragma unroll
        for (int ks = 0; ks < 2; ++ks) {
            #pragma unroll
            for (int mt = 0; mt < 4; ++mt) {
                bf16x8 aW = *(const bf16x8*)(sWp + (mt * 16 + r) * WPITCH + ks * 32 + g * 8);
                #pragma unroll
                for (int nt = 0; nt < 2; ++nt)
                    accP[mt][nt] = MFMA16(aW, aN[nt][ks], accP[mt][nt]);
            }
        }

        // ---- write P^T to LDS with b_parent folded (bias aggregated by adj colsums, per reference) ----
        #pragma unroll
        for (int mt = 0; mt < 4; ++mt) {
            #pragma unroll
            for (int rr = 0; rr < 4; ++rr) {
                int d = mt * 16 + g * 4 + rr;         // C-frag row
                float bpv = sBpar[d];
                myPT[d * KP + r] = (__bf16)(accP[mt][0][rr] + bpv);        // k = r < 16
                int k1 = 16 + r;
                float v1 = (k1 < J) ? (accP[mt][1][rr] + bpv) : 0.f;       // zero pad k=24..31
                myPT[d * KP + k1] = (__bf16)v1;
            }
        }
        __syncthreads();

        // ---- aggregation: agg[j][d] = adjT[j][k] * P^T(B)[k][d], K = 32 ----
        bf16x8 aA0 = *(const bf16x8*)(myAT + r * KP + g * 8);
        bf16x8 aA1 = *(const bf16x8*)(myAT + (16 + r) * KP + g * 8);  // rows >=24 garbage -> rows never stored
        f32x4 accA[2][4];
        #pragma unroll
        for (int mt = 0; mt < 2; ++mt)
            #pragma unroll
            for (int nt = 0; nt < 4; ++nt) accA[mt][nt] = f32x4{0.f, 0.f, 0.f, 0.f};
        #pragma unroll
        for (int nt = 0; nt < 4; ++nt) {
            bf16x8 bP = *(const bf16x8*)(myPT + (nt * 16 + r) * KP + g * 8);
            accA[0][nt] = MFMA16(aA0, bP, accA[0][nt]);
            accA[1][nt] = MFMA16(aA1, bP, accA[1][nt]);
        }

        // ---- epilogue: sigmoid((agg + children + recurrent + biases)/3) ----
        float bs[4];
        #pragma unroll
        for (int nt = 0; nt < 4; ++nt) bs[nt] = sBsum[nt * 16 + r];
        #pragma unroll
        for (int mt = 0; mt < 2; ++mt) {
            #pragma unroll
            for (int rr = 0; rr < 4; ++rr) {
                int j = mt * 16 + g * 4 + rr;
                if (j < J) {
                    float* op = out + (size_t)b * ROW + j * C + r;
                    #pragma unroll
                    for (int nt = 0; nt < 4; ++nt) {
                        float x = (accA[mt][nt][rr] + accCR[mt][nt][rr] + bs[nt]) * (1.0f / 3.0f);
                        float s = __builtin_amdgcn_rcpf(1.0f + __expf(-x));
                        op[nt * 16] = s;
                    }
                }
            }
        }
        __syncthreads();
    }
}

extern "C" void kernel_launch(void* const* d_in, const int* in_sizes, int n_in,
                              void* d_out, int out_size, void* d_ws, size_t ws_size,
                              hipStream_t stream) {
    const float* node = (const float*)d_in[0];
    const float* edge = (const float*)d_in[1];
    const float* adj  = (const float*)d_in[2];
    const float* Wp   = (const float*)d_in[3];
    const float* bpar = (const float*)d_in[4];
    const float* Wr   = (const float*)d_in[5];
    const float* brec = (const float*)d_in[6];
    const float* Wc   = (const float*)d_in[7];
    const float* bch  = (const float*)d_in[8];

    n2e_kernel<<<BLOCKS, 256, 0, stream>>>(node, edge, adj, Wp, bpar, Wr, brec, Wc, bch,
                                           (float*)d_out);
}

// Round 2
// 81.740 us; speedup vs baseline: 1.0875x; 1.0875x over previous
//
#include <hip/hip_runtime.h>
#include <hip/hip_bf16.h>

typedef __bf16 bf16x8 __attribute__((ext_vector_type(8)));
typedef float  f32x4  __attribute__((ext_vector_type(4)));
typedef float  f32x8  __attribute__((ext_vector_type(8)));
typedef unsigned short us4 __attribute__((ext_vector_type(4)));

#define MFMA16(a, b, c) __builtin_amdgcn_mfma_f32_16x16x32_bf16((a), (b), (c), 0, 0, 0)

constexpr int JJ      = 24;
constexpr int CC      = 64;
constexpr int ROW     = JJ * CC;   // 1536
constexpr int WAVES   = 8;         // 512 threads/block
constexpr int BPW     = 2;         // batches per wave
constexpr int BLOCKS  = 16384 / (WAVES * BPW);  // 1024

// LDS: weights k-blocked [ks][d][32] (exact 64B rows, conflict-free b128 B-frag reads)
//      PT per-wave [d=64][k=32] (wave-private -> NO barriers in the loop)

__global__ __launch_bounds__(512, 4) void n2e_kernel(
    const float* __restrict__ node, const float* __restrict__ edge,
    const float* __restrict__ adj,
    const float* __restrict__ Wp, const float* __restrict__ bp,
    const float* __restrict__ Wr, const float* __restrict__ br,
    const float* __restrict__ Wc, const float* __restrict__ bc,
    float* __restrict__ out)
{
    __shared__ __bf16 sWc[2 * 64 * 32];
    __shared__ __bf16 sWr[2 * 64 * 32];
    __shared__ __bf16 sWp[2 * 64 * 32];
    __shared__ float  sBsum[64];
    __shared__ float  sBpar[64];
    __shared__ __bf16 sPT[WAVES * 64 * 32];   // per-wave P^T[d][k]

    const int tid = threadIdx.x;

    // ---- stage weights transposed+k-blocked: sW[(c/32)*2048 + d*32 + c%32] = W[c][d] ----
    for (int idx = tid; idx < 4096; idx += 512) {
        int c = idx >> 6, d = idx & 63;
        int dst = (c >> 5) * 2048 + d * 32 + (c & 31);
        sWc[dst] = (__bf16)Wc[idx];
        sWr[dst] = (__bf16)Wr[idx];
        sWp[dst] = (__bf16)Wp[idx];
    }
    if (tid < 64) { sBsum[tid] = bc[tid] + br[tid]; sBpar[tid] = bp[tid]; }
    __syncthreads();   // the ONLY block-wide barrier

    const int lane = tid & 63;
    const int wave = tid >> 6;
    const int r    = lane & 15;    // frag row/col index
    const int g    = lane >> 4;    // k-group

    __bf16* myPT = sPT + wave * 2048;

    float bs[4], bpv[4];
    #pragma unroll
    for (int nt = 0; nt < 4; ++nt) { bs[nt] = sBsum[nt * 16 + r]; bpv[nt] = sBpar[nt * 16 + r]; }

    for (int it = 0; it < BPW; ++it) {
        const int b = blockIdx.x * (WAVES * BPW) + wave * BPW + it;
        const float* nf = node + (size_t)b * ROW;
        const float* ef = edge + (size_t)b * ROW;
        const float* af = adj  + (size_t)b * (JJ * JJ);

        // ---- node/edge A-frags: A[j][c], j = mt*16+r, c = ks*32+g*8.. ----
        bf16x8 aN[2][2], aE[2][2];
        #pragma unroll
        for (int mt = 0; mt < 2; ++mt) {
            const int row = mt * 16 + r;
            #pragma unroll
            for (int ks = 0; ks < 2; ++ks) {
                bf16x8 an{}, ae{};
                if (row < JJ) {
                    f32x8 x = *(const f32x8*)(nf + row * CC + ks * 32 + g * 8);
                    f32x8 y = *(const f32x8*)(ef + row * CC + ks * 32 + g * 8);
                    #pragma unroll
                    for (int e = 0; e < 8; ++e) { an[e] = (__bf16)x[e]; ae[e] = (__bf16)y[e]; }
                }
                aN[mt][ks] = an; aE[mt][ks] = ae;
            }
        }

        // ---- adj^T A-frags straight from global: A[j][k] = adj[k][j] (k>=24 or j>=24 -> 0) ----
        bf16x8 aA[2];
        #pragma unroll
        for (int mt = 0; mt < 2; ++mt) {
            bf16x8 t{};
            const int j = mt * 16 + r;
            if (g < 3 && j < JJ) {
                #pragma unroll
                for (int e = 0; e < 8; ++e) t[e] = (__bf16)af[(g * 8 + e) * JJ + j];
            }
            aA[mt] = t;
        }

        // ---- children + recurrent: accCR[j-tile][d-tile] ----
        f32x4 accCR[2][4];
        #pragma unroll
        for (int mt = 0; mt < 2; ++mt)
            #pragma unroll
            for (int nt = 0; nt < 4; ++nt) accCR[mt][nt] = f32x4{0.f, 0.f, 0.f, 0.f};
        #pragma unroll
        for (int ks = 0; ks < 2; ++ks) {
            #pragma unroll
            for (int nt = 0; nt < 4; ++nt) {
                bf16x8 bC = *(const bf16x8*)(sWc + ks * 2048 + (nt * 16 + r) * 32 + g * 8);
                bf16x8 bR = *(const bf16x8*)(sWr + ks * 2048 + (nt * 16 + r) * 32 + g * 8);
                #pragma unroll
                for (int mt = 0; mt < 2; ++mt) {
                    accCR[mt][nt] = MFMA16(aN[mt][ks], bC, accCR[mt][nt]);
                    accCR[mt][nt] = MFMA16(aE[mt][ks], bR, accCR[mt][nt]);
                }
            }
        }

        // ---- parent projection (natural orientation): accP[j-tile][d-tile] ----
        f32x4 accP[2][4];
        #pragma unroll
        for (int mt = 0; mt < 2; ++mt)
            #pragma unroll
            for (int nt = 0; nt < 4; ++nt) accP[mt][nt] = f32x4{0.f, 0.f, 0.f, 0.f};
        #pragma unroll
        for (int ks = 0; ks < 2; ++ks) {
            #pragma unroll
            for (int nt = 0; nt < 4; ++nt) {
                bf16x8 bW = *(const bf16x8*)(sWp + ks * 2048 + (nt * 16 + r) * 32 + g * 8);
                #pragma unroll
                for (int mt = 0; mt < 2; ++mt)
                    accP[mt][nt] = MFMA16(aN[mt][ks], bW, accP[mt][nt]);
            }
        }

        // ---- P (+b_parent, masked to real rows) -> wave-private PT[d][k], packed b64 writes ----
        #pragma unroll
        for (int mt = 0; mt < 2; ++mt) {
            const bool addb = (mt == 0) || (g < 2);   // j = mt*16+g*4+rr < 24
            #pragma unroll
            for (int nt = 0; nt < 4; ++nt) {
                us4 w;
                #pragma unroll
                for (int rr = 0; rr < 4; ++rr) {
                    float v = accP[mt][nt][rr];
                    if (addb) v += bpv[nt];
                    w[rr] = __builtin_bit_cast(unsigned short, (__bf16)v);
                }
                *(us4*)(myPT + (nt * 16 + r) * 32 + mt * 16 + g * 4) = w;
            }
        }

        // ---- aggregation: accA[j][d] = adjT x P, accumulated on top of accCR (MFMA C-in) ----
        f32x4 accA[2][4];
        #pragma unroll
        for (int nt = 0; nt < 4; ++nt) {
            bf16x8 bP = *(const bf16x8*)(myPT + (nt * 16 + r) * 32 + g * 8);
            #pragma unroll
            for (int mt = 0; mt < 2; ++mt)
                accA[mt][nt] = MFMA16(aA[mt], bP, accCR[mt][nt]);
        }

        // ---- epilogue: sigmoid((sum + b_child + b_rec)/3), coalesced-ish dword stores ----
        #pragma unroll
        for (int mt = 0; mt < 2; ++mt) {
            #pragma unroll
            for (int rr = 0; rr < 4; ++rr) {
                const int j = mt * 16 + g * 4 + rr;
                if (j < JJ) {
                    float* op = out + (size_t)b * ROW + j * CC + r;
                    #pragma unroll
                    for (int nt = 0; nt < 4; ++nt) {
                        float x = (accA[mt][nt][rr] + bs[nt]) * (1.0f / 3.0f);
                        float s = __builtin_amdgcn_rcpf(1.0f + __expf(-x));
                        op[nt * 16] = s;
                    }
                }
            }
        }
    }
}

extern "C" void kernel_launch(void* const* d_in, const int* in_sizes, int n_in,
                              void* d_out, int out_size, void* d_ws, size_t ws_size,
                              hipStream_t stream) {
    const float* node = (const float*)d_in[0];
    const float* edge = (const float*)d_in[1];
    const float* adj  = (const float*)d_in[2];
    const float* Wp   = (const float*)d_in[3];
    const float* bpar = (const float*)d_in[4];
    const float* Wr   = (const float*)d_in[5];
    const float* brec = (const float*)d_in[6];
    const float* Wc   = (const float*)d_in[7];
    const float* bch  = (const float*)d_in[8];

    n2e_kernel<<<BLOCKS, 512, 0, stream>>>(node, edge, adj, Wp, bpar, Wr, brec, Wc, bch,
                                           (float*)d_out);
}